// Round 13
// baseline (199.105 us; speedup 1.0000x reference)
//
#include <hip/hip_runtime.h>
#include <hip/hip_bf16.h>

// B=4, L=4096, C=1024, H=16, D=64
// GEMM1: qkv = x@Wqkv^T+b  (M=16384,N=3072,K=1024)  -> bf16  [16-wave gemm]
// attn: per-token 16x16 head-attention, writes scrambled layout
// GEMM2: out = scr@Wout^T+b (M=16384,N=1024,K=1024) -> fp32  [8-wave gemm]
//
// Round-13: MIXED config. R12 showed 16-wave (4 waves/SIMD, 64x64/wave) wins
// for G1 (114.9->105.1, MfmaUtil 42.6) but the single-batch G2 regressed
// (~+11): 16-wave serial prologue/epilogue/barrier convoy isn't amortized
// over 1 batch. So: G1 = 16-wave kernel (R12), G2 = 8-wave kernel (R11).
// Both validated in their rounds, absmax identical.

typedef __attribute__((ext_vector_type(8))) short bf16x8;
typedef __attribute__((ext_vector_type(4))) float f32x4;

__device__ __forceinline__ float bf2f(unsigned short u) {
    union { unsigned int i; float f; } x;
    x.i = ((unsigned int)u) << 16;
    return x.f;
}
__device__ __forceinline__ unsigned short f2bf(float f) {
    unsigned int u = __float_as_uint(f);
    u = (u + 0x7FFFu + ((u >> 16) & 1u)) >> 16;   // RNE
    return (unsigned short)u;
}

#define VMCNT4() asm volatile("s_waitcnt vmcnt(4)" ::: "memory")
#define VMCNT2() asm volatile("s_waitcnt vmcnt(2)" ::: "memory")
#define VMCNT0() asm volatile("s_waitcnt vmcnt(0)" ::: "memory")
#define BAR()    __builtin_amdgcn_s_barrier()
#define SCHED0() __builtin_amdgcn_sched_barrier(0)

// ---------------- fused cast fp32 -> bf16 for x, Wqkv, Wout ----------------
__global__ __launch_bounds__(256) void cast_all(const float* __restrict__ x,
                                                const float* __restrict__ wq,
                                                const float* __restrict__ wo,
                                                unsigned short* __restrict__ xb,
                                                unsigned short* __restrict__ wqb,
                                                unsigned short* __restrict__ wob) {
    const size_t base = (size_t)blockIdx.x * 2048 + threadIdx.x;
#pragma unroll
    for (int it = 0; it < 8; ++it) {
        size_t i = base + (size_t)it * 256;
        const float4* s; ushort4* d; size_t off;
        if (i < 4194304)      { s = (const float4*)x;  d = (ushort4*)xb;  off = i; }
        else if (i < 4980736) { s = (const float4*)wq; d = (ushort4*)wqb; off = i - 4194304; }
        else                  { s = (const float4*)wo; d = (ushort4*)wob; off = i - 4980736; }
        float4 v = s[off];
        ushort4 o;
        o.x = f2bf(v.x); o.y = f2bf(v.y); o.z = f2bf(v.z); o.w = f2bf(v.w);
        d[off] = o;
    }
}

// ============ 16-wave 256^2 single-sync NT GEMM (GEMM1) ============
// Wave (wr,wc) in 4x4 grid owns rows wr*64..+63, cols wc*64..+63.
// LDS half-tile = [128 rows][64 cols]; swizzle slot s @ row r = chunk s^(r&7).
__global__ __launch_bounds__(1024, 1) void gemm_w16(const unsigned short* __restrict__ A,
                                                    const unsigned short* __restrict__ B,
                                                    const float* __restrict__ bias,
                                                    unsigned short* __restrict__ Cb,
                                                    int N, int K, int NXT) {
    __shared__ __align__(16) unsigned short lds[2][2][2][8192];

    const int tid  = threadIdx.x;
    const int lane = tid & 63;
    const int wave = tid >> 6;
    const int wr = wave >> 2;        // 0..3
    const int wc = wave & 3;         // 0..3
    const int fr = lane & 15;
    const int fq = lane >> 4;
    const int ha = wr >> 1;
    const int hb = wc >> 1;

    const int nwg  = gridDim.x;
    const int orig = blockIdx.x;
    const int wg   = (orig & 7) * (nwg >> 3) + (orig >> 3);
    const int tileM = (wg / NXT) * 256;
    const int tileN = (wg % NXT) * 256;

    const int r8  = tid >> 3;                 // row 0..127
    const int jsw = (tid & 7) ^ (r8 & 7);
    const unsigned short* Ap = A;
    const unsigned short* Bp = B;

#define STAGE16(nb, OPp, HH, ktt) do {                                                 \
    const unsigned short* gb = (OPp) ? Bp : Ap;                                        \
    const int rb = ((OPp) ? tileN : tileM) + (HH) * 128 + r8;                          \
    const unsigned short* s0 = gb + (size_t)rb * K + (ktt) * 64 + jsw * 8;             \
    unsigned short* d0 = &lds[nb][OPp][HH][tid * 8];                                   \
    __builtin_amdgcn_global_load_lds((const __attribute__((address_space(1))) void*)s0,\
        (__attribute__((address_space(3))) void*)d0, 16, 0, 0);                        \
} while (0)

#define READ_K16(bb, ks) do {                                                          \
    _Pragma("unroll") for (int i2 = 0; i2 < 4; ++i2) {                                 \
        const int lr = (wr & 1) * 64 + i2 * 16 + fr;                                   \
        af[i2] = *(const bf16x8*)&lds[bb][0][ha][lr * 64 + ((((ks)*4+fq) ^ (lr & 7)) << 3)];\
    }                                                                                  \
    _Pragma("unroll") for (int j2 = 0; j2 < 4; ++j2) {                                 \
        const int lc = (wc & 1) * 64 + j2 * 16 + fr;                                   \
        bf[j2] = *(const bf16x8*)&lds[bb][1][hb][lc * 64 + ((((ks)*4+fq) ^ (lc & 7)) << 3)];\
    }                                                                                  \
} while (0)

#define MFMA_K16() do {                                                                \
    __builtin_amdgcn_s_setprio(1);                                                     \
    _Pragma("unroll") for (int i2 = 0; i2 < 4; ++i2)                                   \
    _Pragma("unroll") for (int j2 = 0; j2 < 4; ++j2)                                   \
        acc[i2][j2] = __builtin_amdgcn_mfma_f32_16x16x32_bf16(af[i2], bf[j2],          \
                                                              acc[i2][j2], 0, 0, 0);   \
    __builtin_amdgcn_s_setprio(0);                                                     \
} while (0)

    f32x4 acc[4][4];
#pragma unroll
    for (int i = 0; i < 4; ++i)
#pragma unroll
        for (int j = 0; j < 4; ++j) acc[i][j] = (f32x4){0.f, 0.f, 0.f, 0.f};

    STAGE16(0, 0, 0, 0);
    STAGE16(0, 1, 0, 0);
    STAGE16(0, 1, 1, 0);
    STAGE16(0, 0, 1, 0);

    const int NT = K >> 6;
    int cur = 0;
    for (int kt = 0; kt < NT - 1; ++kt) {
        const int nb = cur ^ 1;
        BAR();
        STAGE16(nb, 0, 0, kt + 1);
        STAGE16(nb, 1, 0, kt + 1);
        VMCNT2();
        BAR();
        SCHED0();
        bf16x8 af[4], bf[4];
        READ_K16(cur, 0); MFMA_K16();
        STAGE16(nb, 1, 1, kt + 1);
        STAGE16(nb, 0, 1, kt + 1);
        READ_K16(cur, 1); MFMA_K16();
        cur = nb;
    }
    BAR();
    VMCNT0();
    BAR();
    SCHED0();
    {
        bf16x8 af[4], bf[4];
        READ_K16(cur, 0); MFMA_K16();
        READ_K16(cur, 1); MFMA_K16();
    }

#pragma unroll
    for (int i = 0; i < 4; ++i) {
        const int row = tileM + wr * 64 + i * 16 + fq * 4;
#pragma unroll
        for (int j = 0; j < 4; ++j) {
            const int col = tileN + wc * 64 + j * 16 + fr;
            const float bv = bias[col];
#pragma unroll
            for (int r = 0; r < 4; ++r)
                Cb[(size_t)(row + r) * N + col] = f2bf(acc[i][j][r] + bv);
        }
    }
#undef STAGE16
#undef READ_K16
#undef MFMA_K16
}

// ============ 8-wave 256^2 single-sync NT GEMM (GEMM2, fp32 out) ============
__global__ __launch_bounds__(512, 2) void gemm_w8(const unsigned short* __restrict__ A,
                                                  const unsigned short* __restrict__ B,
                                                  const float* __restrict__ bias,
                                                  float* __restrict__ Cf,
                                                  int N, int K, int NXT) {
    __shared__ __align__(16) unsigned short lds[2][2][2][8192];

    const int tid  = threadIdx.x;
    const int lane = tid & 63;
    const int wave = tid >> 6;
    const int wr = wave >> 2;        // 0..1
    const int wc = wave & 3;         // 0..3
    const int fr = lane & 15;
    const int fq = lane >> 4;
    const int frx = fr & 7;

    const int nwg  = gridDim.x;
    const int orig = blockIdx.x;
    const int wg   = (orig & 7) * (nwg >> 3) + (orig >> 3);
    const int tileM = (wg / NXT) * 256;
    const int tileN = (wg % NXT) * 256;

    const int r8  = tid >> 3;
    const int jsw = (tid & 7) ^ (r8 & 7);
    const unsigned short* Ap = A;
    const unsigned short* Bp = B;

#define STAGE8(nb, OPp, HH, ktt) do {                                                  \
    const unsigned short* gb = (OPp) ? Bp : Ap;                                        \
    const int rb = ((OPp) ? tileN : tileM) + (HH) * 128 + r8;                          \
    const unsigned short* s0 = gb + (size_t)rb * K + (ktt) * 64 + jsw * 8;             \
    unsigned short* d0 = &lds[nb][OPp][HH][tid * 8];                                   \
    __builtin_amdgcn_global_load_lds((const __attribute__((address_space(1))) void*)s0,\
        (__attribute__((address_space(3))) void*)d0, 16, 0, 0);                        \
    __builtin_amdgcn_global_load_lds(                                                  \
        (const __attribute__((address_space(1))) void*)(s0 + (size_t)64 * K),          \
        (__attribute__((address_space(3))) void*)(d0 + 4096), 16, 0, 0);               \
} while (0)

#define READ_A8(bb, h) do {                                                            \
    _Pragma("unroll") for (int i2 = 0; i2 < 4; ++i2) {                                 \
        const int ar = (wr * 64 + i2 * 16 + fr) * 64;                                  \
        af[i2][0] = *(const bf16x8*)&lds[bb][0][h][ar + ((fq ^ frx) << 3)];            \
        af[i2][1] = *(const bf16x8*)&lds[bb][0][h][ar + (((4 + fq) ^ frx) << 3)];      \
    }                                                                                  \
} while (0)

#define READ_B8(bb, g) do {                                                            \
    _Pragma("unroll") for (int j2 = 0; j2 < 2; ++j2) {                                 \
        const int br = (wc * 32 + j2 * 16 + fr) * 64;                                  \
        bfr[2*(g)+j2][0] = *(const bf16x8*)&lds[bb][1][g][br + ((fq ^ frx) << 3)];     \
        bfr[2*(g)+j2][1] = *(const bf16x8*)&lds[bb][1][g][br + (((4 + fq) ^ frx) << 3)];\
    }                                                                                  \
} while (0)

#define MFMA_Q8(h, g) do {                                                             \
    __builtin_amdgcn_s_setprio(1);                                                     \
    _Pragma("unroll") for (int i2 = 0; i2 < 4; ++i2)                                   \
    _Pragma("unroll") for (int j2 = 0; j2 < 2; ++j2) {                                 \
        acc[(h)*4+i2][(g)*2+j2] = __builtin_amdgcn_mfma_f32_16x16x32_bf16(             \
            af[i2][0], bfr[2*(g)+j2][0], acc[(h)*4+i2][(g)*2+j2], 0, 0, 0);            \
        acc[(h)*4+i2][(g)*2+j2] = __builtin_amdgcn_mfma_f32_16x16x32_bf16(             \
            af[i2][1], bfr[2*(g)+j2][1], acc[(h)*4+i2][(g)*2+j2], 0, 0, 0);            \
    }                                                                                  \
    __builtin_amdgcn_s_setprio(0);                                                     \
} while (0)

    f32x4 acc[8][4];
#pragma unroll
    for (int i = 0; i < 8; ++i)
#pragma unroll
        for (int j = 0; j < 4; ++j) acc[i][j] = (f32x4){0.f, 0.f, 0.f, 0.f};

    STAGE8(0, 0, 0, 0);
    STAGE8(0, 1, 0, 0);
    STAGE8(0, 1, 1, 0);
    STAGE8(0, 0, 1, 0);

    const int NT = K >> 6;
    int cur = 0;
    for (int kt = 0; kt < NT - 1; ++kt) {
        const int nb = cur ^ 1;
        BAR();
        STAGE8(nb, 0, 0, kt + 1);
        STAGE8(nb, 1, 0, kt + 1);
        VMCNT4();
        BAR();
        SCHED0();
        bf16x8 af[4][2], bfr[4][2];
        READ_A8(cur, 0); READ_B8(cur, 0); READ_B8(cur, 1);
        MFMA_Q8(0, 0);
        STAGE8(nb, 1, 1, kt + 1);
        STAGE8(nb, 0, 1, kt + 1);
        MFMA_Q8(0, 1);
        READ_A8(cur, 1);
        MFMA_Q8(1, 0);
        MFMA_Q8(1, 1);
        cur = nb;
    }
    BAR();
    VMCNT0();
    BAR();
    SCHED0();
    {
        bf16x8 af[4][2], bfr[4][2];
        READ_A8(cur, 0); READ_B8(cur, 0); READ_B8(cur, 1);
        MFMA_Q8(0, 0);
        MFMA_Q8(0, 1);
        READ_A8(cur, 1);
        MFMA_Q8(1, 0);
        MFMA_Q8(1, 1);
    }

#pragma unroll
    for (int i = 0; i < 8; ++i) {
        const int row = tileM + (i >> 2) * 128 + wr * 64 + (i & 3) * 16 + fq * 4;
#pragma unroll
        for (int j = 0; j < 4; ++j) {
            const int col = tileN + (j >> 1) * 128 + wc * 32 + (j & 1) * 16 + fr;
            const float bv = bias[col];
#pragma unroll
            for (int r = 0; r < 4; ++r)
                Cf[(size_t)(row + r) * N + col] = acc[i][j][r] + bv;
        }
    }
#undef STAGE8
#undef READ_A8
#undef READ_B8
#undef MFMA_Q8
}

// ---------------- per-token head-attention (R8 version) ----------------
__global__ __launch_bounds__(256) void attn_kernel(const unsigned short* __restrict__ qkv,
                                                   unsigned short* __restrict__ scr) {
    __shared__ __align__(16) unsigned short sbuf[4][3328];
    __shared__ float Pl[4][256];

    const int wave = threadIdx.x >> 6, lane = threadIdx.x & 63;
    const int token = blockIdx.x * 4 + wave;
    const int b = token >> 12, l = token & 4095;

    const unsigned short* src = qkv + (size_t)token * 3072;
    unsigned short* sw = sbuf[wave];
#pragma unroll
    for (int i = 0; i < 2; ++i) {
        const int c = lane + i * 64;
        const int row = c >> 3, j8 = (c & 7) * 8;
        *(bf16x8*)&sw[row * 72 + j8]        = *(const bf16x8*)&src[c * 8];
        *(bf16x8*)&sw[1152 + row * 72 + j8] = *(const bf16x8*)&src[1024 + c * 8];
        *(bf16x8*)&sw[2304 + c * 8]         = *(const bf16x8*)&src[2048 + c * 8];
    }
    __syncthreads();

    float sv[4];
#pragma unroll
    for (int r = 0; r < 4; ++r) {
        const int p = r * 64 + lane;
        const int h = p >> 4, g = p & 15;
        float acc = 0.f;
#pragma unroll
        for (int d8 = 0; d8 < 8; ++d8) {
            bf16x8 qa = *(const bf16x8*)&sw[h * 72 + d8 * 8];
            bf16x8 kb = *(const bf16x8*)&sw[1152 + g * 72 + d8 * 8];
#pragma unroll
            for (int j = 0; j < 8; ++j)
                acc += bf2f((unsigned short)qa[j]) * bf2f((unsigned short)kb[j]);
        }
        sv[r] = acc * 0.125f;
    }

#pragma unroll
    for (int r = 0; r < 4; ++r) {
        float m = sv[r];
        m = fmaxf(m, __shfl_xor(m, 1));
        m = fmaxf(m, __shfl_xor(m, 2));
        m = fmaxf(m, __shfl_xor(m, 4));
        m = fmaxf(m, __shfl_xor(m, 8));
        float e = __expf(sv[r] - m);
        float s = e;
        s += __shfl_xor(s, 1);
        s += __shfl_xor(s, 2);
        s += __shfl_xor(s, 4);
        s += __shfl_xor(s, 8);
        Pl[wave][r * 64 + lane] = e / s;
    }
    __syncthreads();

    float vreg[16];
#pragma unroll
    for (int g = 0; g < 16; ++g) vreg[g] = bf2f(sw[2304 + g * 64 + lane]);

    const int q_ = l >> 4, j = l & 15;
    const size_t base = ((size_t)b * 4096 + q_) * 1024 + j * 64 + lane;
#pragma unroll
    for (int h = 0; h < 16; ++h) {
        float acc = 0.f;
#pragma unroll
        for (int g = 0; g < 16; ++g) acc += Pl[wave][h * 16 + g] * vreg[g];
        scr[base + (size_t)h * 256 * 1024] = f2bf(acc);
    }
}

// ---------------- launch ----------------
extern "C" void kernel_launch(void* const* d_in, const int* in_sizes, int n_in,
                              void* d_out, int out_size, void* d_ws, size_t ws_size,
                              hipStream_t stream) {
    const float* x    = (const float*)d_in[0];
    const float* Wqkv = (const float*)d_in[1];
    const float* bqkv = (const float*)d_in[2];
    const float* Wout = (const float*)d_in[3];
    const float* bout = (const float*)d_in[4];
    float* out = (float*)d_out;

    char* ws = (char*)d_ws;
    unsigned short* xb   = (unsigned short*)(ws);
    unsigned short* wqb  = (unsigned short*)(ws + 33554432);
    unsigned short* wob  = (unsigned short*)(ws + 39845888);
    unsigned short* qkvb = (unsigned short*)(ws + 41943040);
    unsigned short* scr  = (unsigned short*)(ws + 142606336);

    cast_all<<<2560, 256, 0, stream>>>(x, Wqkv, Wout, xb, wqb, wob);

    // qkv = x @ Wqkv^T + bqkv  (M=16384, N=3072, K=1024), bf16 out; 16-wave
    gemm_w16<<<768, 1024, 0, stream>>>(xb, wqb, bqkv, qkvb, 3072, 1024, 12);

    // per-token head attention -> scrambled layout
    attn_kernel<<<4096, 256, 0, stream>>>(qkvb, scr);

    // out = scr @ Wout^T + bout  (M=16384, N=1024, K=1024), fp32 out; 8-wave
    gemm_w8<<<256, 512, 0, stream>>>(scr, wob, bout, out, 1024, 1024, 4);
}

// Round 14
// 195.135 us; speedup vs baseline: 1.0203x; 1.0203x over previous
//
#include <hip/hip_runtime.h>
#include <hip/hip_bf16.h>

// B=4, L=4096, C=1024, H=16, D=64
// GEMM1: qkv = x@Wqkv^T+b  (M=16384,N=3072,K=1024)  -> bf16
// attn: per-token 16x16 head-attention, writes scrambled layout
// GEMM2: out = scr@Wout^T+b (M=16384,N=1024,K=1024) -> fp32
//
// Round-14: FINAL — restore R11, the globally best-measured config (196.0us).
// R13's lesson: G1-16-wave is -10us in isolation but splitting the template
// into two named kernels inflated the residual +13us (rule #19 co-compilation
// perturbation); totals across all configs R5-R13 span 196.0-199.6. This
// single-template 8-wave artifact is the best composed binary.
// gemm256: 256x256 tile, BK=64, 8 waves, 128KiB LDS dbuf, single-sync K-tile
// (2 barriers + 1 counted vmcnt(4)), XOR bank swizzle (T2, both-sides),
// bijective XCD swizzle (T1), setprio (T5). attn: 72-stride Q/K (conflict-
// free), wave-parallel softmax, scrambled-layout direct write.

typedef __attribute__((ext_vector_type(8))) short bf16x8;
typedef __attribute__((ext_vector_type(4))) float f32x4;

__device__ __forceinline__ float bf2f(unsigned short u) {
    union { unsigned int i; float f; } x;
    x.i = ((unsigned int)u) << 16;
    return x.f;
}
__device__ __forceinline__ unsigned short f2bf(float f) {
    unsigned int u = __float_as_uint(f);
    u = (u + 0x7FFFu + ((u >> 16) & 1u)) >> 16;   // RNE
    return (unsigned short)u;
}

#define VMCNT4() asm volatile("s_waitcnt vmcnt(4)" ::: "memory")
#define VMCNT0() asm volatile("s_waitcnt vmcnt(0)" ::: "memory")
#define BAR()    __builtin_amdgcn_s_barrier()
#define SCHED0() __builtin_amdgcn_sched_barrier(0)

// ---------------- fused cast fp32 -> bf16 for x, Wqkv, Wout ----------------
__global__ __launch_bounds__(256) void cast_all(const float* __restrict__ x,
                                                const float* __restrict__ wq,
                                                const float* __restrict__ wo,
                                                unsigned short* __restrict__ xb,
                                                unsigned short* __restrict__ wqb,
                                                unsigned short* __restrict__ wob) {
    const size_t base = (size_t)blockIdx.x * 2048 + threadIdx.x;
#pragma unroll
    for (int it = 0; it < 8; ++it) {
        size_t i = base + (size_t)it * 256;
        const float4* s; ushort4* d; size_t off;
        if (i < 4194304)      { s = (const float4*)x;  d = (ushort4*)xb;  off = i; }
        else if (i < 4980736) { s = (const float4*)wq; d = (ushort4*)wqb; off = i - 4194304; }
        else                  { s = (const float4*)wo; d = (ushort4*)wob; off = i - 4980736; }
        float4 v = s[off];
        ushort4 o;
        o.x = f2bf(v.x); o.y = f2bf(v.y); o.z = f2bf(v.z); o.w = f2bf(v.w);
        d[off] = o;
    }
}

// ---------------- 256^2 single-sync deep-pipelined NT GEMM ----------------
// C[m,n] = sum_k A[m,k]*B[n,k] + bias[n]
// LDS half-tile = [128 rows][64 cols] bf16 = 16KB; chunk = 16B (8 bf16).
// Swizzle: LDS slot s at row r holds global chunk j = s ^ (r&7).
template<int OUTF32>
__global__ __launch_bounds__(512, 2) void gemm256(const unsigned short* __restrict__ A,
                                                  const unsigned short* __restrict__ B,
                                                  const float* __restrict__ bias,
                                                  unsigned short* __restrict__ Cb,
                                                  float* __restrict__ Cf,
                                                  int M, int N, int K, int NXT) {
    __shared__ __align__(16) unsigned short lds[2][2][2][8192]; // [buf][A/B][half][128*64]

    const int tid  = threadIdx.x;
    const int lane = tid & 63;
    const int wave = tid >> 6;
    const int wr = wave >> 2;        // 0..1  (M side)
    const int wc = wave & 3;         // 0..3  (N side)
    const int fr = lane & 15;
    const int fq = lane >> 4;
    const int frx = fr & 7;

    // T1: bijective XCD swizzle (grid size % 8 == 0 at all call sites)
    const int nwg  = gridDim.x;
    const int orig = blockIdx.x;
    const int wg   = (orig & 7) * (nwg >> 3) + (orig >> 3);
    const int tileM = (wg / NXT) * 256;
    const int tileN = (wg % NXT) * 256;

    // staging: thread covers chunks tid and tid+512 of a half-tile
    const int r8  = tid >> 3;                 // row 0..63 (first load), +64 second
    const int jsw = (tid & 7) ^ (r8 & 7);     // pre-swizzled global chunk index
    const unsigned short* Ap = A;
    const unsigned short* Bp = B;

#define STAGE(nb, OPp, HH, ktt) do {                                                   \
    const unsigned short* gb = (OPp) ? Bp : Ap;                                        \
    const int rb = ((OPp) ? tileN : tileM) + (HH) * 128 + r8;                          \
    const unsigned short* s0 = gb + (size_t)rb * K + (ktt) * 64 + jsw * 8;             \
    unsigned short* d0 = &lds[nb][OPp][HH][tid * 8];                                   \
    __builtin_amdgcn_global_load_lds((const __attribute__((address_space(1))) void*)s0,\
        (__attribute__((address_space(3))) void*)d0, 16, 0, 0);                        \
    __builtin_amdgcn_global_load_lds(                                                  \
        (const __attribute__((address_space(1))) void*)(s0 + (size_t)64 * K),          \
        (__attribute__((address_space(3))) void*)(d0 + 4096), 16, 0, 0);               \
} while (0)

// read A-half h of buffer bb into af (8 x b128)
#define READ_A(bb, h) do {                                                             \
    _Pragma("unroll") for (int i2 = 0; i2 < 4; ++i2) {                                 \
        const int ar = (wr * 64 + i2 * 16 + fr) * 64;                                  \
        af[i2][0] = *(const bf16x8*)&lds[bb][0][h][ar + ((fq ^ frx) << 3)];            \
        af[i2][1] = *(const bf16x8*)&lds[bb][0][h][ar + (((4 + fq) ^ frx) << 3)];      \
    }                                                                                  \
} while (0)

// read B-half g of buffer bb into bfr[2g..2g+1] (4 x b128)
#define READ_B(bb, g) do {                                                             \
    _Pragma("unroll") for (int j2 = 0; j2 < 2; ++j2) {                                 \
        const int br = (wc * 32 + j2 * 16 + fr) * 64;                                  \
        bfr[2*(g)+j2][0] = *(const bf16x8*)&lds[bb][1][g][br + ((fq ^ frx) << 3)];     \
        bfr[2*(g)+j2][1] = *(const bf16x8*)&lds[bb][1][g][br + (((4 + fq) ^ frx) << 3)];\
    }                                                                                  \
} while (0)

#define MFMA_Q(h, g) do {                                                              \
    __builtin_amdgcn_s_setprio(1);                                                     \
    _Pragma("unroll") for (int i2 = 0; i2 < 4; ++i2)                                   \
    _Pragma("unroll") for (int j2 = 0; j2 < 2; ++j2) {                                 \
        acc[(h)*4+i2][(g)*2+j2] = __builtin_amdgcn_mfma_f32_16x16x32_bf16(             \
            af[i2][0], bfr[2*(g)+j2][0], acc[(h)*4+i2][(g)*2+j2], 0, 0, 0);            \
        acc[(h)*4+i2][(g)*2+j2] = __builtin_amdgcn_mfma_f32_16x16x32_bf16(             \
            af[i2][1], bfr[2*(g)+j2][1], acc[(h)*4+i2][(g)*2+j2], 0, 0, 0);            \
    }                                                                                  \
    __builtin_amdgcn_s_setprio(0);                                                     \
} while (0)

    f32x4 acc[8][4];
#pragma unroll
    for (int i = 0; i < 8; ++i)
#pragma unroll
        for (int j = 0; j < 4; ++j) acc[i][j] = (f32x4){0.f, 0.f, 0.f, 0.f};

    // prologue: stage all 4 halves of tile 0 (8 loads) -> steady invariant E=8
    STAGE(0, 0, 0, 0);
    STAGE(0, 1, 0, 0);
    STAGE(0, 1, 1, 0);
    STAGE(0, 0, 1, 0);

    const int NT = K >> 6;
    int cur = 0;
    for (int kt = 0; kt < NT - 1; ++kt) {
        const int nb = cur ^ 1;
        BAR();                              // BAR1: close t-1's reads of nb
        STAGE(nb, 0, 0, kt + 1);            // A0(t+1)
        STAGE(nb, 1, 0, kt + 1);            // B0(t+1)   (out = 12)
        VMCNT4();                           // tile t's 8 loads landed (deep lead)
        BAR();                              // BAR2: publish tile t
        SCHED0();
        bf16x8 af[4][2], bfr[4][2];
        READ_A(cur, 0); READ_B(cur, 0); READ_B(cur, 1);
        MFMA_Q(0, 0);
        STAGE(nb, 1, 1, kt + 1);            // B1(t+1)
        STAGE(nb, 0, 1, kt + 1);            // A1(t+1)   (out = 8)
        MFMA_Q(0, 1);
        READ_A(cur, 1);
        MFMA_Q(1, 0);
        MFMA_Q(1, 1);
        cur = nb;
    }
    // last tile: no stages; drain its 8 loads once
    BAR();
    VMCNT0();
    BAR();
    SCHED0();
    {
        bf16x8 af[4][2], bfr[4][2];
        READ_A(cur, 0); READ_B(cur, 0); READ_B(cur, 1);
        MFMA_Q(0, 0);
        MFMA_Q(0, 1);
        READ_A(cur, 1);
        MFMA_Q(1, 0);
        MFMA_Q(1, 1);
    }

    // epilogue: C/D layout col=lane&15, row=(lane>>4)*4+reg
#pragma unroll
    for (int i = 0; i < 8; ++i) {
        const int row = tileM + (i >> 2) * 128 + wr * 64 + (i & 3) * 16 + fq * 4;
#pragma unroll
        for (int j = 0; j < 4; ++j) {
            const int col = tileN + (j >> 1) * 128 + wc * 32 + (j & 1) * 16 + fr;
            const float bv = bias[col];
#pragma unroll
            for (int r = 0; r < 4; ++r) {
                const float v = acc[i][j][r] + bv;
                if (OUTF32) Cf[(size_t)(row + r) * N + col] = v;
                else        Cb[(size_t)(row + r) * N + col] = f2bf(v);
            }
        }
    }
#undef STAGE
#undef READ_A
#undef READ_B
#undef MFMA_Q
}

// ---------------- per-token head-attention (R8 version) ----------------
// One token per wave, 4 waves/block. qkv row layout: [3][16][64] bf16.
// LDS: Q rows 72-stride @0, K rows 72-stride @1152, V dense @2304.
// Writes the SCRAMBLED layout: scr[(b*4096 + 256*h + (l>>4))*1024 + (l&15)*64 + d]
__global__ __launch_bounds__(256) void attn_kernel(const unsigned short* __restrict__ qkv,
                                                   unsigned short* __restrict__ scr) {
    __shared__ __align__(16) unsigned short sbuf[4][3328];
    __shared__ float Pl[4][256];

    const int wave = threadIdx.x >> 6, lane = threadIdx.x & 63;
    const int token = blockIdx.x * 4 + wave;
    const int b = token >> 12, l = token & 4095;

    const unsigned short* src = qkv + (size_t)token * 3072;
    unsigned short* sw = sbuf[wave];
#pragma unroll
    for (int i = 0; i < 2; ++i) {
        const int c = lane + i * 64;           // chunk 0..127 (8 bf16 each)
        const int row = c >> 3, j8 = (c & 7) * 8;
        *(bf16x8*)&sw[row * 72 + j8]        = *(const bf16x8*)&src[c * 8];          // Q
        *(bf16x8*)&sw[1152 + row * 72 + j8] = *(const bf16x8*)&src[1024 + c * 8];   // K
        *(bf16x8*)&sw[2304 + c * 8]         = *(const bf16x8*)&src[2048 + c * 8];   // V
    }
    __syncthreads();

    float sv[4];
#pragma unroll
    for (int r = 0; r < 4; ++r) {
        const int p = r * 64 + lane;
        const int h = p >> 4, g = p & 15;
        float acc = 0.f;
#pragma unroll
        for (int d8 = 0; d8 < 8; ++d8) {
            bf16x8 qa = *(const bf16x8*)&sw[h * 72 + d8 * 8];
            bf16x8 kb = *(const bf16x8*)&sw[1152 + g * 72 + d8 * 8];
#pragma unroll
            for (int j = 0; j < 8; ++j)
                acc += bf2f((unsigned short)qa[j]) * bf2f((unsigned short)kb[j]);
        }
        sv[r] = acc * 0.125f;   // scale = 64^-0.5
    }

#pragma unroll
    for (int r = 0; r < 4; ++r) {
        float m = sv[r];
        m = fmaxf(m, __shfl_xor(m, 1));
        m = fmaxf(m, __shfl_xor(m, 2));
        m = fmaxf(m, __shfl_xor(m, 4));
        m = fmaxf(m, __shfl_xor(m, 8));
        float e = __expf(sv[r] - m);
        float s = e;
        s += __shfl_xor(s, 1);
        s += __shfl_xor(s, 2);
        s += __shfl_xor(s, 4);
        s += __shfl_xor(s, 8);
        Pl[wave][r * 64 + lane] = e / s;
    }
    __syncthreads();

    float vreg[16];
#pragma unroll
    for (int g = 0; g < 16; ++g) vreg[g] = bf2f(sw[2304 + g * 64 + lane]);

    const int q_ = l >> 4, j = l & 15;
    const size_t base = ((size_t)b * 4096 + q_) * 1024 + j * 64 + lane;
#pragma unroll
    for (int h = 0; h < 16; ++h) {
        float acc = 0.f;
#pragma unroll
        for (int g = 0; g < 16; ++g) acc += Pl[wave][h * 16 + g] * vreg[g];
        scr[base + (size_t)h * 256 * 1024] = f2bf(acc);
    }
}

// ---------------- launch ----------------
extern "C" void kernel_launch(void* const* d_in, const int* in_sizes, int n_in,
                              void* d_out, int out_size, void* d_ws, size_t ws_size,
                              hipStream_t stream) {
    const float* x    = (const float*)d_in[0];   // [4,4096,1024]
    const float* Wqkv = (const float*)d_in[1];   // [3072,1024]
    const float* bqkv = (const float*)d_in[2];   // [3072]
    const float* Wout = (const float*)d_in[3];   // [1024,1024]
    const float* bout = (const float*)d_in[4];   // [1024]
    float* out = (float*)d_out;                  // [4,4096,1024] fp32

    char* ws = (char*)d_ws;
    unsigned short* xb   = (unsigned short*)(ws);
    unsigned short* wqb  = (unsigned short*)(ws + 33554432);
    unsigned short* wob  = (unsigned short*)(ws + 39845888);
    unsigned short* qkvb = (unsigned short*)(ws + 41943040);
    unsigned short* scr  = (unsigned short*)(ws + 142606336);

    cast_all<<<2560, 256, 0, stream>>>(x, Wqkv, Wout, xb, wqb, wob);

    // qkv = x @ Wqkv^T + bqkv  (M=16384, N=3072, K=1024), bf16 out; 768 blocks
    gemm256<0><<<768, 512, 0, stream>>>(xb, wqb, bqkv, qkvb, nullptr, 16384, 3072, 1024, 12);

    // per-token head attention -> scrambled layout
    attn_kernel<<<4096, 256, 0, stream>>>(qkvb, scr);

    // out = scr @ Wout^T + bout  (M=16384, N=1024, K=1024), fp32 out; 256 blocks
    gemm256<1><<<256, 512, 0, stream>>>(scr, wob, bout, nullptr, out, 16384, 1024, 1024, 4);
}